// Round 8
// baseline (407.801 us; speedup 1.0000x reference)
//
#include <hip/hip_runtime.h>
#include <math.h>

// FlowMatchingLoss: B=8, M=K=2048. Log-domain pre-scaled by log2e (hw exp2/log2).
//   K_log' = sc_b * c,  sc_b = -20*log2e/(cmax_b+1e-8)
// Round-8: (1) fix barrier: tree-broadcast + per-group local spin with backoff
// (round-7's 512 pollers on ONE L3 line cost ~20us/barrier = 265us total);
// (2) hoist row-constant sc*|A|^2 (+lu in final) out of exp2 into the log2
// epilogue; (3) packed-f32 row pairs (v_pk_fma_f32 via ext_vector fma).
// Co-residency of all 512 blocks guaranteed: __launch_bounds__(512,4) caps
// VGPR at 128 => 2 blocks/CU; LDS 41KB => 3/CU; 8 waves => 4/CU.

#define LOG2E 1.4426950408889634f
#define TAU   0.95238095238095238f     // 1/(1+0.05)
#define NEG20LOG2E (-28.853900817779268f)

typedef float v2f __attribute__((ext_vector_type(2)));

// workspace layout, 4-byte units
enum : int {
  OFF_PA4   = 0,        // B*M float4: x0.xyz, |x0|^2
  OFF_PB4   = 65536,    // B*K float4: xgt.xyz, |xgt|^2
  OFF_A     = 131072,   // a = sigmoid(10*tanh(alpha/10))
  OFF_LA2   = 147456,   // log2(max(a,1e-30))
  OFF_LU    = 163840,   // log_u * log2e
  OFF_LV    = 180224,   // log_v * log2e
  OFF_CPART = 196608,   // 512 per-block cmax partials (64/batch)
  OFF_SUMAP = 197120,   // 256 per-wave sum(a) partials (32/batch)
  OFF_SWP   = 197376,   // 256 per-wave sum(w)
  OFF_SEWP  = 197632,   // 256 per-wave sum(w*err)
  OFF_FPART = 197888,   // 3*512 final partials (bce, sum_pi, sum_pi*klog)
  OFF_BAR   = 199424,   // 1024 garr (32 grp x 32 stride) | 32 root | 1024 grel
  OFF_END   = 201536
};

__device__ __forceinline__ float fexp2(float x){ return __builtin_amdgcn_exp2f(x); }
__device__ __forceinline__ float flog2(float x){ return __builtin_amdgcn_logf(x); }

__device__ __forceinline__ float wave_sum(float v){
  #pragma unroll
  for(int m=32;m;m>>=1) v += __shfl_xor(v,m,64);
  return v;
}
__device__ __forceinline__ float wave_max(float v){
  #pragma unroll
  for(int m=32;m;m>>=1) v = fmaxf(v,__shfl_xor(v,m,64));
  return v;
}

// grid barrier: 32 group arrive ctrs (16 blocks each) -> root (32) ->
// broadcast to 32 per-group release flags; leaders spin on THEIR group's
// flag only (16 pollers/line) with s_sleep backoff. Monotonic per launch.
__device__ __forceinline__ void gbar(unsigned* bar, int phase, int blk){
  __syncthreads();
  if(threadIdx.x == 0){
    __threadfence();                               // release data (agent)
    const int g = blk & 31;
    unsigned* garr = bar + g*32;
    unsigned* root = bar + 1024;
    unsigned* grel = bar + 1056 + g*32;
    const unsigned va = __hip_atomic_fetch_add(garr, 1u, __ATOMIC_ACQ_REL,
                                               __HIP_MEMORY_SCOPE_AGENT);
    if(va == (unsigned)(16*(phase+1) - 1)){
      const unsigned vr = __hip_atomic_fetch_add(root, 1u, __ATOMIC_ACQ_REL,
                                                 __HIP_MEMORY_SCOPE_AGENT);
      if(vr == (unsigned)(32*(phase+1) - 1)){
        #pragma unroll 4
        for(int g2=0; g2<32; ++g2)
          __hip_atomic_store(bar + 1056 + g2*32, (unsigned)(phase+1),
                             __ATOMIC_RELAXED, __HIP_MEMORY_SCOPE_AGENT);
      }
    }
    while(__hip_atomic_load(grel, __ATOMIC_RELAXED, __HIP_MEMORY_SCOPE_AGENT)
          < (unsigned)(phase+1))
      __builtin_amdgcn_s_sleep(4);
    __threadfence();                               // acquire
  }
  __syncthreads();
}

__global__ __launch_bounds__(256) void k_init(float* ws){
  unsigned* bar = reinterpret_cast<unsigned*>(ws) + OFF_BAR;
  for(int i=threadIdx.x;i<2112;i+=256) bar[i] = 0u;
}

// one lse half-iteration; row-constant sc*|A|^2 hoisted to epilogue;
// row pairs via packed f32.
#define LSE_PASS(ROWV, FIRSTV, PH) {                                          \
    const float4* pP = reinterpret_cast<const float4*>(                       \
                         ws + (ROWV?OFF_PB4:OFF_PA4)) + 2048*b;               \
    const float*  lo = ws + (ROWV?OFF_LV:OFF_LU) + 2048*b;                    \
    float* op = ws + (ROWV?OFF_LU:OFF_LV);                                    \
    const float4 A0=ROWV?AR[0]:AC[0], A1=ROWV?AR[1]:AC[1],                    \
                 A2=ROWV?AR[2]:AC[2], A3=ROWV?AR[3]:AC[3];                    \
    for(int i=tid;i<2048;i+=512){                                             \
      const float4 q = pP[i];                                                 \
      const float lvi = FIRSTV ? 0.0f : lo[i];                                \
      sB[i] = make_float4(n2sc*q.x, n2sc*q.y, n2sc*q.z, fmaf(sc,q.w,lvi));    \
    }                                                                         \
    __syncthreads();                                                          \
    const v2f ax01={A0.x,A1.x}, ay01={A0.y,A1.y}, az01={A0.z,A1.z};           \
    const v2f ax23={A2.x,A3.x}, ay23={A2.y,A3.y}, az23={A2.z,A3.z};           \
    v2f s01={0.0f,0.0f}, s23={0.0f,0.0f};                                     \
    _Pragma("unroll 2")                                                       \
    for(int k=lane;k<2048;k+=64){                                             \
      const float4 pt = sB[k];                                                \
      const v2f px={pt.x,pt.x}, py={pt.y,pt.y}, pz={pt.z,pt.z},               \
                pw={pt.w,pt.w};                                               \
      const v2f c01 = __builtin_elementwise_fma(ax01,px,                      \
                      __builtin_elementwise_fma(ay01,py,                      \
                      __builtin_elementwise_fma(az01,pz,pw)));                \
      const v2f c23 = __builtin_elementwise_fma(ax23,px,                      \
                      __builtin_elementwise_fma(ay23,py,                      \
                      __builtin_elementwise_fma(az23,pz,pw)));                \
      s01 += (v2f){fexp2(c01.x), fexp2(c01.y)};                               \
      s23 += (v2f){fexp2(c23.x), fexp2(c23.y)};                               \
    }                                                                         \
    const float s0=wave_sum(s01.x), s1=wave_sum(s01.y);                       \
    const float s2=wave_sum(s23.x), s3=wave_sum(s23.y);                       \
    if(lane==0){                                                              \
      op[r0  ] = TAU*((ROWV?ws[OFF_LA2+r0  ]:lb2) - fmaf(sc,A0.w,flog2(s0))); \
      op[r0+1] = TAU*((ROWV?ws[OFF_LA2+r0+1]:lb2) - fmaf(sc,A1.w,flog2(s1))); \
      op[r0+2] = TAU*((ROWV?ws[OFF_LA2+r0+2]:lb2) - fmaf(sc,A2.w,flog2(s2))); \
      op[r0+3] = TAU*((ROWV?ws[OFF_LA2+r0+3]:lb2) - fmaf(sc,A3.w,flog2(s3))); \
    }                                                                         \
    gbar(bar, PH, blk);                                                       \
  }

__global__ __launch_bounds__(512,4) void k_fused(const float* __restrict__ x0,
                                                 const float* __restrict__ xgt,
                                                 const float* __restrict__ vp,
                                                 const float* __restrict__ ap,
                                                 const float* __restrict__ mxp,
                                                 float* __restrict__ ws,
                                                 float* __restrict__ out){
  __shared__ float4 sB[2048];
  __shared__ float  sL[2048];
  __shared__ float  sred[24];
  const int blk = blockIdx.x, tid = threadIdx.x, lane = tid&63, wid = tid>>6;
  const int b  = blk>>6;                          // batch (64 blocks/batch)
  const int r0 = b*2048 + (blk&63)*32 + (wid<<2); // global row of this wave
  unsigned* bar = reinterpret_cast<unsigned*>(ws) + OFF_BAR;
  float4* pA4 = reinterpret_cast<float4*>(ws+OFF_PA4);
  float4* pB4 = reinterpret_cast<float4*>(ws+OFF_PB4);

  // ---- P0: prep (blocks 0-31; one point per thread) ----
  if(blk < 32){
    const int idx = blk*512 + tid;
    const float x = x0[idx*3], y = x0[idx*3+1], z = x0[idx*3+2];
    pA4[idx] = make_float4(x,y,z, x*x+y*y+z*z);
    const float gx = xgt[idx*3], gy = xgt[idx*3+1], gz = xgt[idx*3+2];
    pB4[idx] = make_float4(gx,gy,gz, gx*gx+gy*gy+gz*gz);
    const float al = ap[idx];
    const float a = 1.0f/(1.0f + fexp2(-10.0f*tanhf(al*0.1f)*LOG2E));
    ws[OFF_A  +idx] = a;
    ws[OFF_LA2+idx] = flog2(fmaxf(a,1e-30f));
    const float w = 1.0f/(1.0f + fexp2(-al*LOG2E));
    const float tx = mxp[idx*3]-x,  ty = mxp[idx*3+1]-y,  tz = mxp[idx*3+2]-z;
    const float dx = vp[idx*3]-tx,  dy = vp[idx*3+1]-ty,  dz = vp[idx*3+2]-tz;
    const float se = dx*dx+dy*dy+dz*dz;
    const float sa = wave_sum(a), sw = wave_sum(w), sew = wave_sum(se*w);
    if(lane == 0){
      const int slot = blk*8 + wid;               // 256 slots, 32/batch
      ws[OFF_SUMAP+slot] = sa;
      ws[OFF_SWP  +slot] = sw;
      ws[OFF_SEWP +slot] = sew;
    }
  }
  gbar(bar, 0, blk);

  // ---- P1: cmax (raw points) ----
  float4 AR[4];
  #pragma unroll
  for(int r=0;r<4;r++) AR[r] = pA4[r0+r];         // persistent row fragments
  {
    const float4* pB = pB4 + 2048*b;
    for(int i=tid;i<2048;i+=512) sB[i] = pB[i];
    __syncthreads();
    float c0=0,c1=0,c2=0,c3=0;                    // init 0 == clamp at 0
    #pragma unroll 2
    for(int k=lane;k<2048;k+=64){
      const float4 pt = sB[k];
      float d;
      d = AR[0].x*pt.x+AR[0].y*pt.y+AR[0].z*pt.z; c0=fmaxf(c0, AR[0].w+pt.w-2.0f*d);
      d = AR[1].x*pt.x+AR[1].y*pt.y+AR[1].z*pt.z; c1=fmaxf(c1, AR[1].w+pt.w-2.0f*d);
      d = AR[2].x*pt.x+AR[2].y*pt.y+AR[2].z*pt.z; c2=fmaxf(c2, AR[2].w+pt.w-2.0f*d);
      d = AR[3].x*pt.x+AR[3].y*pt.y+AR[3].z*pt.z; c3=fmaxf(c3, AR[3].w+pt.w-2.0f*d);
    }
    const float cmv = wave_max(fmaxf(fmaxf(c0,c1),fmaxf(c2,c3)));
    if(lane==0) sred[wid] = cmv;
    __syncthreads();
    if(tid==0){
      float m = sred[0];
      #pragma unroll
      for(int i=1;i<8;i++) m = fmaxf(m, sred[i]);
      ws[OFF_CPART+blk] = m;
    }
  }
  gbar(bar, 1, blk);

  // ---- per-batch constants, once, kept in registers ----
  const float cm = wave_max(ws[OFF_CPART + b*64 + lane]);
  const float sc = NEG20LOG2E/(cm + 1e-8f);
  const float n2sc = -2.0f*sc;
  float sav = (lane<32) ? ws[OFF_SUMAP + b*32 + lane] : 0.0f;
  sav = wave_sum(sav);
  const float lb2 = flog2(fmaxf(sav*(1.0f/2048.0f), 1e-30f));
  float4 AC[4];
  #pragma unroll
  for(int r=0;r<4;r++) AC[r] = pB4[r0+r];         // col-side row fragments

  // ---- P2..P11: 5 Sinkhorn iterations (row, col) ----
  LSE_PASS(true,  true,  2)
  LSE_PASS(false, false, 3)
  LSE_PASS(true,  false, 4)
  LSE_PASS(false, false, 5)
  LSE_PASS(true,  false, 6)
  LSE_PASS(false, false, 7)
  LSE_PASS(true,  false, 8)
  LSE_PASS(false, false, 9)
  LSE_PASS(true,  false, 10)
  LSE_PASS(false, false, 11)

  // ---- P12: final pi pass (sc|A|^2+lu hoisted; per-row S,Q,L accums) ----
  {
    const float4* pB = pB4 + 2048*b;
    const float* lv = ws + OFF_LV + 2048*b;
    for(int i=tid;i<2048;i+=512){
      const float4 q = pB[i];
      const float lvi = lv[i];
      sB[i] = make_float4(n2sc*q.x, n2sc*q.y, n2sc*q.z, fmaf(sc,q.w,lvi));
      sL[i] = lvi;
    }
    __syncthreads();
    const float lu0=ws[OFF_LU+r0],   lu1=ws[OFF_LU+r0+1];
    const float lu2=ws[OFF_LU+r0+2], lu3=ws[OFF_LU+r0+3];
    const v2f ax01={AR[0].x,AR[1].x}, ay01={AR[0].y,AR[1].y}, az01={AR[0].z,AR[1].z};
    const v2f ax23={AR[2].x,AR[3].x}, ay23={AR[2].y,AR[3].y}, az23={AR[2].z,AR[3].z};
    v2f S01={0.0f,0.0f},S23={0.0f,0.0f};   // sum exp2(argp)
    v2f Q01={0.0f,0.0f},Q23={0.0f,0.0f};   // sum exp2(argp)*argp
    v2f L01={0.0f,0.0f},L23={0.0f,0.0f};   // sum exp2(argp)*lv_k
    #pragma unroll 2
    for(int k=lane;k<2048;k+=64){
      const float4 pt = sB[k];
      const float lvk = sL[k];
      const v2f px={pt.x,pt.x}, py={pt.y,pt.y}, pz={pt.z,pt.z}, pw={pt.w,pt.w};
      const v2f lk={lvk,lvk};
      const v2f c01 = __builtin_elementwise_fma(ax01,px,
                      __builtin_elementwise_fma(ay01,py,
                      __builtin_elementwise_fma(az01,pz,pw)));
      const v2f c23 = __builtin_elementwise_fma(ax23,px,
                      __builtin_elementwise_fma(ay23,py,
                      __builtin_elementwise_fma(az23,pz,pw)));
      const v2f p01 = {fexp2(c01.x), fexp2(c01.y)};
      const v2f p23 = {fexp2(c23.x), fexp2(c23.y)};
      S01 += p01;                      S23 += p23;
      Q01 = __builtin_elementwise_fma(p01,c01,Q01);
      Q23 = __builtin_elementwise_fma(p23,c23,Q23);
      L01 = __builtin_elementwise_fma(p01,lk,L01);
      L23 = __builtin_elementwise_fma(p23,lk,L23);
    }
    float S[4]={wave_sum(S01.x),wave_sum(S01.y),wave_sum(S23.x),wave_sum(S23.y)};
    float Q[4]={wave_sum(Q01.x),wave_sum(Q01.y),wave_sum(Q23.x),wave_sum(Q23.y)};
    float L[4]={wave_sum(L01.x),wave_sum(L01.y),wave_sum(L23.x),wave_sum(L23.y)};
    const float lus[4]={lu0,lu1,lu2,lu3};
    float spc = 0.0f, bce = 0.0f, spt = 0.0f;
    #pragma unroll
    for(int r=0;r<4;r++){
      const int row = r0 + r;
      const float cr = fmaf(sc, AR[r].w, lus[r]);   // hoisted row constant
      const float p2 = fexp2(cr);
      const float sp = p2*S[r];                     // true row sum of pi
      // sum(pi*arg_true) contribution: p2*(Q + cr*S); klog = arg_true-lu-lv
      spc += p2*fmaf(cr,S[r],Q[r]) - p2*L[r] - lus[r]*sp;
      float yv = sp / (ws[OFF_A+row] + 1e-8f);
      yv = fminf(fmaxf(yv,0.0f),1.0f);
      const float al = ap[row];
      bce += fmaxf(al,0.0f) - al*yv
           + 0.69314718056f*flog2(1.0f + fexp2(-fabsf(al)*LOG2E));
      spt += sp;
    }
    if(lane==0){ sred[wid]=bce; sred[8+wid]=spt; sred[16+wid]=spc; }
    __syncthreads();
    if(tid==0){
      float tb=0, ts=0, tc=0;
      #pragma unroll
      for(int i=0;i<8;i++){ tb+=sred[i]; ts+=sred[8+i]; tc+=sred[16+i]; }
      ws[OFF_FPART +        blk] = tb;
      ws[OFF_FPART + 512  + blk] = ts;
      ws[OFF_FPART + 1024 + blk] = tc;
    }
  }
  gbar(bar, 12, blk);

  // ---- P13: combine (block 0 only) ----
  if(blk == 0){
    float pb = ws[OFF_FPART+tid];
    float ps = ws[OFF_FPART+512+tid];
    float pc = ws[OFF_FPART+1024+tid];
    float pw = (tid<256) ? ws[OFF_SWP+tid]  : 0.0f;
    float pe = (tid<256) ? ws[OFF_SEWP+tid] : 0.0f;
    pb=wave_sum(pb); ps=wave_sum(ps); pc=wave_sum(pc);
    pw=wave_sum(pw); pe=wave_sum(pe);
    if(lane==0){
      sL[wid*5+0]=pb; sL[wid*5+1]=ps; sL[wid*5+2]=pc;
      sL[wid*5+3]=pw; sL[wid*5+4]=pe;
    }
    __syncthreads();
    if(tid==0){
      float bce=0, sp=0, spc=0, sw=0, sew=0;
      #pragma unroll
      for(int w=0;w<8;w++){
        bce+=sL[w*5+0]; sp+=sL[w*5+1]; spc+=sL[w*5+2];
        sw +=sL[w*5+3]; sew+=sL[w*5+4];
      }
      const float loss_vel  = sew / fmaxf(sw, 1.0f);
      const float loss_surv = bce / 16384.0f;
      // sum(pi*cost_n) = spc * (-ln2/20)  since klog = -20*log2e*cost_n
      const float loss_tr = (spc * (-0.03465735902799726f)) / fmaxf(sp, 1e-8f);
      out[0] = loss_vel + loss_surv + 0.1f*loss_tr;
    }
  }
}

extern "C" void kernel_launch(void* const* d_in, const int* in_sizes, int n_in,
                              void* d_out, int out_size, void* d_ws, size_t ws_size,
                              hipStream_t stream) {
  (void)in_sizes; (void)n_in; (void)out_size; (void)ws_size;
  const float* x0  = (const float*)d_in[0];
  const float* xgt = (const float*)d_in[1];
  const float* vp  = (const float*)d_in[2];
  const float* ap  = (const float*)d_in[3];
  const float* mxp = (const float*)d_in[5];   // t (d_in[4]) unused
  float* ws  = (float*)d_ws;
  float* out = (float*)d_out;

  k_init<<<1, 256, 0, stream>>>(ws);          // zero barrier counters/flags

  k_fused<<<512, 512, 0, stream>>>(x0, xgt, vp, ap, mxp, ws, out);
}

// Round 9
// 124.341 us; speedup vs baseline: 3.2797x; 3.2797x over previous
//
#include <hip/hip_runtime.h>
#include <math.h>

// FlowMatchingLoss: B=8, M=K=2048. Log-domain pre-scaled by log2e (hw exp2/log2).
//   K_log' = sc_b * c,  sc_b = -20*log2e/(cmax_b+1e-8)
// Round-9: FENCE-FREE grid barriers. Round 7/8 showed the cost is cache
// maintenance (threadfence => per-leader L2 wb/inv; acq_rel made it worse),
// not spin contention. Fix: ALL cross-phase mutable data (LU/LV, partials,
// and the write-once PA4/PB4/A/LA2) is WRITTEN via relaxed agent-scope atomic
// stores (bypass L2 -> L3 is the single source of truth; no dirty L2 lines
// anywhere). Mutable arrays are READ via relaxed agent atomic loads; the
// write-once arrays via normal cached loads (safe: L2s are invalidated at
// kernel start and no block reads them before the barrier after their write).
// Barrier then needs only instruction ordering: s_waitcnt vmcnt(0) + relaxed
// tree arrive/release. Zero wbl2/inv in the whole kernel.

#define LOG2E 1.4426950408889634f
#define TAU   0.95238095238095238f     // 1/(1+0.05)
#define NEG20LOG2E (-28.853900817779268f)

typedef float v2f __attribute__((ext_vector_type(2)));

// workspace layout, 4-byte units
enum : int {
  OFF_PA4   = 0,        // B*M float4: x0.xyz, |x0|^2
  OFF_PB4   = 65536,    // B*K float4: xgt.xyz, |xgt|^2
  OFF_A     = 131072,   // a = sigmoid(10*tanh(alpha/10))
  OFF_LA2   = 147456,   // log2(max(a,1e-30))
  OFF_LU    = 163840,   // log_u * log2e      (L3-resident via atomics)
  OFF_LV    = 180224,   // log_v * log2e      (L3-resident via atomics)
  OFF_CPART = 196608,   // 512 per-block cmax partials (64/batch)
  OFF_SUMAP = 197120,   // 256 per-wave sum(a) partials (32/batch)
  OFF_SWP   = 197376,   // 256 per-wave sum(w)
  OFF_SEWP  = 197632,   // 256 per-wave sum(w*err)
  OFF_FPART = 197888,   // 3*512 final partials (bce, sum_pi, sum_pi*klog)
  OFF_BAR   = 199424,   // 1024 garr (32 grp x 32 stride) | 32 root | 1024 grel
  OFF_END   = 201536
};

__device__ __forceinline__ float fexp2(float x){ return __builtin_amdgcn_exp2f(x); }
__device__ __forceinline__ float flog2(float x){ return __builtin_amdgcn_logf(x); }

// L3-coherent access (relaxed agent atomics = cache-bypass load/store,
// NO cache-maintenance instructions)
__device__ __forceinline__ float ld3(const float* p){
  return __hip_atomic_load(p, __ATOMIC_RELAXED, __HIP_MEMORY_SCOPE_AGENT);
}
__device__ __forceinline__ void st3(float* p, float v){
  __hip_atomic_store(p, v, __ATOMIC_RELAXED, __HIP_MEMORY_SCOPE_AGENT);
}

__device__ __forceinline__ float wave_sum(float v){
  #pragma unroll
  for(int m=32;m;m>>=1) v += __shfl_xor(v,m,64);
  return v;
}
__device__ __forceinline__ float wave_max(float v){
  #pragma unroll
  for(int m=32;m;m>>=1) v = fmaxf(v,__shfl_xor(v,m,64));
  return v;
}

// fence-free grid barrier: vmcnt drain -> tree arrive (32 groups of 16 ->
// root) -> broadcast to 32 per-group release flags -> local spin (16
// pollers/line). Monotonic per launch; counters zeroed by k_init.
__device__ __forceinline__ void gbar(unsigned* bar, int phase, int blk){
  __syncthreads();
  if(threadIdx.x == 0){
    asm volatile("s_waitcnt vmcnt(0)" ::: "memory");   // stores reached L3
    const int g = blk & 31;
    unsigned* garr = bar + g*32;
    unsigned* root = bar + 1024;
    unsigned* grel = bar + 1056 + g*32;
    const unsigned va = __hip_atomic_fetch_add(garr, 1u, __ATOMIC_RELAXED,
                                               __HIP_MEMORY_SCOPE_AGENT);
    if(va == (unsigned)(16*(phase+1) - 1)){
      const unsigned vr = __hip_atomic_fetch_add(root, 1u, __ATOMIC_RELAXED,
                                                 __HIP_MEMORY_SCOPE_AGENT);
      if(vr == (unsigned)(32*(phase+1) - 1)){
        #pragma unroll 8
        for(int g2=0; g2<32; ++g2)
          __hip_atomic_store(bar + 1056 + g2*32, (unsigned)(phase+1),
                             __ATOMIC_RELAXED, __HIP_MEMORY_SCOPE_AGENT);
      }
    }
    while(__hip_atomic_load(grel, __ATOMIC_RELAXED, __HIP_MEMORY_SCOPE_AGENT)
          < (unsigned)(phase+1))
      __builtin_amdgcn_s_sleep(1);
    asm volatile("" ::: "memory");
  }
  __syncthreads();
}

__global__ __launch_bounds__(256) void k_init(float* ws){
  unsigned* bar = reinterpret_cast<unsigned*>(ws) + OFF_BAR;
  for(int i=threadIdx.x;i<2112;i+=256) bar[i] = 0u;
}

// one lse half-iteration; row-constant sc*|A|^2 hoisted to epilogue;
// row pairs via packed f32; lo read L3-atomic, output written L3-atomic.
#define LSE_PASS(ROWV, FIRSTV, PH) {                                          \
    const float4* pP = reinterpret_cast<const float4*>(                       \
                         ws + (ROWV?OFF_PB4:OFF_PA4)) + 2048*b;               \
    float* lo = ws + (ROWV?OFF_LV:OFF_LU) + 2048*b;                           \
    float* op = ws + (ROWV?OFF_LU:OFF_LV);                                    \
    const float4 A0=ROWV?AR[0]:AC[0], A1=ROWV?AR[1]:AC[1],                    \
                 A2=ROWV?AR[2]:AC[2], A3=ROWV?AR[3]:AC[3];                    \
    for(int i=tid;i<2048;i+=512){                                             \
      const float4 q = pP[i];                                                 \
      const float lvi = FIRSTV ? 0.0f : ld3(lo+i);                            \
      sB[i] = make_float4(n2sc*q.x, n2sc*q.y, n2sc*q.z, fmaf(sc,q.w,lvi));    \
    }                                                                         \
    __syncthreads();                                                          \
    const v2f ax01={A0.x,A1.x}, ay01={A0.y,A1.y}, az01={A0.z,A1.z};           \
    const v2f ax23={A2.x,A3.x}, ay23={A2.y,A3.y}, az23={A2.z,A3.z};           \
    v2f s01={0.0f,0.0f}, s23={0.0f,0.0f};                                     \
    _Pragma("unroll 2")                                                       \
    for(int k=lane;k<2048;k+=64){                                             \
      const float4 pt = sB[k];                                                \
      const v2f px={pt.x,pt.x}, py={pt.y,pt.y}, pz={pt.z,pt.z},               \
                pw={pt.w,pt.w};                                               \
      const v2f c01 = __builtin_elementwise_fma(ax01,px,                      \
                      __builtin_elementwise_fma(ay01,py,                      \
                      __builtin_elementwise_fma(az01,pz,pw)));                \
      const v2f c23 = __builtin_elementwise_fma(ax23,px,                      \
                      __builtin_elementwise_fma(ay23,py,                      \
                      __builtin_elementwise_fma(az23,pz,pw)));                \
      s01 += (v2f){fexp2(c01.x), fexp2(c01.y)};                               \
      s23 += (v2f){fexp2(c23.x), fexp2(c23.y)};                               \
    }                                                                         \
    const float s0=wave_sum(s01.x), s1=wave_sum(s01.y);                       \
    const float s2=wave_sum(s23.x), s3=wave_sum(s23.y);                       \
    if(lane==0){                                                              \
      st3(op+r0  , TAU*((ROWV?ws[OFF_LA2+r0  ]:lb2) - fmaf(sc,A0.w,flog2(s0))));\
      st3(op+r0+1, TAU*((ROWV?ws[OFF_LA2+r0+1]:lb2) - fmaf(sc,A1.w,flog2(s1))));\
      st3(op+r0+2, TAU*((ROWV?ws[OFF_LA2+r0+2]:lb2) - fmaf(sc,A2.w,flog2(s2))));\
      st3(op+r0+3, TAU*((ROWV?ws[OFF_LA2+r0+3]:lb2) - fmaf(sc,A3.w,flog2(s3))));\
    }                                                                         \
    gbar(bar, PH, blk);                                                       \
  }

__global__ __launch_bounds__(512,4) void k_fused(const float* __restrict__ x0,
                                                 const float* __restrict__ xgt,
                                                 const float* __restrict__ vp,
                                                 const float* __restrict__ ap,
                                                 const float* __restrict__ mxp,
                                                 float* __restrict__ ws,
                                                 float* __restrict__ out){
  __shared__ float4 sB[2048];
  __shared__ float  sL[2048];
  __shared__ float  sred[24];
  const int blk = blockIdx.x, tid = threadIdx.x, lane = tid&63, wid = tid>>6;
  const int b  = blk>>6;                          // batch (64 blocks/batch)
  const int r0 = b*2048 + (blk&63)*32 + (wid<<2); // global row of this wave
  unsigned* bar = reinterpret_cast<unsigned*>(ws) + OFF_BAR;
  float4* pA4 = reinterpret_cast<float4*>(ws+OFF_PA4);
  float4* pB4 = reinterpret_cast<float4*>(ws+OFF_PB4);

  // ---- P0: prep (blocks 0-31); all outputs via L3 atomic stores ----
  if(blk < 32){
    const int idx = blk*512 + tid;
    float* qa = ws + OFF_PA4 + idx*4;
    float* qb = ws + OFF_PB4 + idx*4;
    const float x = x0[idx*3], y = x0[idx*3+1], z = x0[idx*3+2];
    st3(qa+0,x); st3(qa+1,y); st3(qa+2,z); st3(qa+3, x*x+y*y+z*z);
    const float gx = xgt[idx*3], gy = xgt[idx*3+1], gz = xgt[idx*3+2];
    st3(qb+0,gx); st3(qb+1,gy); st3(qb+2,gz); st3(qb+3, gx*gx+gy*gy+gz*gz);
    const float al = ap[idx];
    const float a = 1.0f/(1.0f + fexp2(-10.0f*tanhf(al*0.1f)*LOG2E));
    st3(ws+OFF_A  +idx, a);
    st3(ws+OFF_LA2+idx, flog2(fmaxf(a,1e-30f)));
    const float w = 1.0f/(1.0f + fexp2(-al*LOG2E));
    const float tx = mxp[idx*3]-x,  ty = mxp[idx*3+1]-y,  tz = mxp[idx*3+2]-z;
    const float dx = vp[idx*3]-tx,  dy = vp[idx*3+1]-ty,  dz = vp[idx*3+2]-tz;
    const float se = dx*dx+dy*dy+dz*dz;
    const float sa = wave_sum(a), sw = wave_sum(w), sew = wave_sum(se*w);
    if(lane == 0){
      const int slot = blk*8 + wid;               // 256 slots, 32/batch
      st3(ws+OFF_SUMAP+slot, sa);
      st3(ws+OFF_SWP  +slot, sw);
      st3(ws+OFF_SEWP +slot, sew);
    }
  }
  gbar(bar, 0, blk);

  // ---- P1: cmax (normal cached reads of PA4/PB4: clean L3-backed) ----
  float4 AR[4];
  #pragma unroll
  for(int r=0;r<4;r++) AR[r] = pA4[r0+r];         // persistent row fragments
  {
    const float4* pB = pB4 + 2048*b;
    for(int i=tid;i<2048;i+=512) sB[i] = pB[i];
    __syncthreads();
    float c0=0,c1=0,c2=0,c3=0;                    // init 0 == clamp at 0
    #pragma unroll 2
    for(int k=lane;k<2048;k+=64){
      const float4 pt = sB[k];
      float d;
      d = AR[0].x*pt.x+AR[0].y*pt.y+AR[0].z*pt.z; c0=fmaxf(c0, AR[0].w+pt.w-2.0f*d);
      d = AR[1].x*pt.x+AR[1].y*pt.y+AR[1].z*pt.z; c1=fmaxf(c1, AR[1].w+pt.w-2.0f*d);
      d = AR[2].x*pt.x+AR[2].y*pt.y+AR[2].z*pt.z; c2=fmaxf(c2, AR[2].w+pt.w-2.0f*d);
      d = AR[3].x*pt.x+AR[3].y*pt.y+AR[3].z*pt.z; c3=fmaxf(c3, AR[3].w+pt.w-2.0f*d);
    }
    const float cmv = wave_max(fmaxf(fmaxf(c0,c1),fmaxf(c2,c3)));
    if(lane==0) sred[wid] = cmv;
    __syncthreads();
    if(tid==0){
      float m = sred[0];
      #pragma unroll
      for(int i=1;i<8;i++) m = fmaxf(m, sred[i]);
      st3(ws+OFF_CPART+blk, m);
    }
  }
  gbar(bar, 1, blk);

  // ---- per-batch constants, once, kept in registers ----
  const float cm = wave_max(ld3(ws+OFF_CPART + b*64 + lane));
  const float sc = NEG20LOG2E/(cm + 1e-8f);
  const float n2sc = -2.0f*sc;
  float sav = (lane<32) ? ld3(ws+OFF_SUMAP + b*32 + lane) : 0.0f;
  sav = wave_sum(sav);
  const float lb2 = flog2(fmaxf(sav*(1.0f/2048.0f), 1e-30f));
  float4 AC[4];
  #pragma unroll
  for(int r=0;r<4;r++) AC[r] = pB4[r0+r];         // col-side row fragments

  // ---- P2..P11: 5 Sinkhorn iterations (row, col) ----
  LSE_PASS(true,  true,  2)
  LSE_PASS(false, false, 3)
  LSE_PASS(true,  false, 4)
  LSE_PASS(false, false, 5)
  LSE_PASS(true,  false, 6)
  LSE_PASS(false, false, 7)
  LSE_PASS(true,  false, 8)
  LSE_PASS(false, false, 9)
  LSE_PASS(true,  false, 10)
  LSE_PASS(false, false, 11)

  // ---- P12: final pi pass (sc|A|^2+lu hoisted; per-row S,Q,L accums) ----
  {
    const float4* pB = pB4 + 2048*b;
    float* lv = ws + OFF_LV + 2048*b;
    for(int i=tid;i<2048;i+=512){
      const float4 q = pB[i];
      const float lvi = ld3(lv+i);
      sB[i] = make_float4(n2sc*q.x, n2sc*q.y, n2sc*q.z, fmaf(sc,q.w,lvi));
      sL[i] = lvi;
    }
    __syncthreads();
    const float lu0=ld3(ws+OFF_LU+r0),   lu1=ld3(ws+OFF_LU+r0+1);
    const float lu2=ld3(ws+OFF_LU+r0+2), lu3=ld3(ws+OFF_LU+r0+3);
    const v2f ax01={AR[0].x,AR[1].x}, ay01={AR[0].y,AR[1].y}, az01={AR[0].z,AR[1].z};
    const v2f ax23={AR[2].x,AR[3].x}, ay23={AR[2].y,AR[3].y}, az23={AR[2].z,AR[3].z};
    v2f S01={0.0f,0.0f},S23={0.0f,0.0f};   // sum exp2(argp)
    v2f Q01={0.0f,0.0f},Q23={0.0f,0.0f};   // sum exp2(argp)*argp
    v2f L01={0.0f,0.0f},L23={0.0f,0.0f};   // sum exp2(argp)*lv_k
    #pragma unroll 2
    for(int k=lane;k<2048;k+=64){
      const float4 pt = sB[k];
      const float lvk = sL[k];
      const v2f px={pt.x,pt.x}, py={pt.y,pt.y}, pz={pt.z,pt.z}, pw={pt.w,pt.w};
      const v2f lk={lvk,lvk};
      const v2f c01 = __builtin_elementwise_fma(ax01,px,
                      __builtin_elementwise_fma(ay01,py,
                      __builtin_elementwise_fma(az01,pz,pw)));
      const v2f c23 = __builtin_elementwise_fma(ax23,px,
                      __builtin_elementwise_fma(ay23,py,
                      __builtin_elementwise_fma(az23,pz,pw)));
      const v2f p01 = {fexp2(c01.x), fexp2(c01.y)};
      const v2f p23 = {fexp2(c23.x), fexp2(c23.y)};
      S01 += p01;                      S23 += p23;
      Q01 = __builtin_elementwise_fma(p01,c01,Q01);
      Q23 = __builtin_elementwise_fma(p23,c23,Q23);
      L01 = __builtin_elementwise_fma(p01,lk,L01);
      L23 = __builtin_elementwise_fma(p23,lk,L23);
    }
    float S[4]={wave_sum(S01.x),wave_sum(S01.y),wave_sum(S23.x),wave_sum(S23.y)};
    float Q[4]={wave_sum(Q01.x),wave_sum(Q01.y),wave_sum(Q23.x),wave_sum(Q23.y)};
    float L[4]={wave_sum(L01.x),wave_sum(L01.y),wave_sum(L23.x),wave_sum(L23.y)};
    const float lus[4]={lu0,lu1,lu2,lu3};
    float spc = 0.0f, bce = 0.0f, spt = 0.0f;
    #pragma unroll
    for(int r=0;r<4;r++){
      const int row = r0 + r;
      const float cr = fmaf(sc, AR[r].w, lus[r]);   // hoisted row constant
      const float p2 = fexp2(cr);
      const float sp = p2*S[r];                     // true row sum of pi
      // sum(pi*arg_true) = p2*(Q + cr*S); klog = arg_true - lu - lv
      spc += p2*fmaf(cr,S[r],Q[r]) - p2*L[r] - lus[r]*sp;
      float yv = sp / (ws[OFF_A+row] + 1e-8f);
      yv = fminf(fmaxf(yv,0.0f),1.0f);
      const float al = ap[row];
      bce += fmaxf(al,0.0f) - al*yv
           + 0.69314718056f*flog2(1.0f + fexp2(-fabsf(al)*LOG2E));
      spt += sp;
    }
    if(lane==0){ sred[wid]=bce; sred[8+wid]=spt; sred[16+wid]=spc; }
    __syncthreads();
    if(tid==0){
      float tb=0, ts=0, tc=0;
      #pragma unroll
      for(int i=0;i<8;i++){ tb+=sred[i]; ts+=sred[8+i]; tc+=sred[16+i]; }
      st3(ws+OFF_FPART +        blk, tb);
      st3(ws+OFF_FPART + 512  + blk, ts);
      st3(ws+OFF_FPART + 1024 + blk, tc);
    }
  }
  gbar(bar, 12, blk);

  // ---- P13: combine (block 0 only) ----
  if(blk == 0){
    float pb = ld3(ws+OFF_FPART+tid);
    float ps = ld3(ws+OFF_FPART+512+tid);
    float pc = ld3(ws+OFF_FPART+1024+tid);
    float pw = (tid<256) ? ld3(ws+OFF_SWP+tid)  : 0.0f;
    float pe = (tid<256) ? ld3(ws+OFF_SEWP+tid) : 0.0f;
    pb=wave_sum(pb); ps=wave_sum(ps); pc=wave_sum(pc);
    pw=wave_sum(pw); pe=wave_sum(pe);
    if(lane==0){
      sL[wid*5+0]=pb; sL[wid*5+1]=ps; sL[wid*5+2]=pc;
      sL[wid*5+3]=pw; sL[wid*5+4]=pe;
    }
    __syncthreads();
    if(tid==0){
      float bce=0, sp=0, spc=0, sw=0, sew=0;
      #pragma unroll
      for(int w=0;w<8;w++){
        bce+=sL[w*5+0]; sp+=sL[w*5+1]; spc+=sL[w*5+2];
        sw +=sL[w*5+3]; sew+=sL[w*5+4];
      }
      const float loss_vel  = sew / fmaxf(sw, 1.0f);
      const float loss_surv = bce / 16384.0f;
      // sum(pi*cost_n) = spc * (-ln2/20)  since klog = -20*log2e*cost_n
      const float loss_tr = (spc * (-0.03465735902799726f)) / fmaxf(sp, 1e-8f);
      out[0] = loss_vel + loss_surv + 0.1f*loss_tr;
    }
  }
}

extern "C" void kernel_launch(void* const* d_in, const int* in_sizes, int n_in,
                              void* d_out, int out_size, void* d_ws, size_t ws_size,
                              hipStream_t stream) {
  (void)in_sizes; (void)n_in; (void)out_size; (void)ws_size;
  const float* x0  = (const float*)d_in[0];
  const float* xgt = (const float*)d_in[1];
  const float* vp  = (const float*)d_in[2];
  const float* ap  = (const float*)d_in[3];
  const float* mxp = (const float*)d_in[5];   // t (d_in[4]) unused
  float* ws  = (float*)d_ws;
  float* out = (float*)d_out;

  k_init<<<1, 256, 0, stream>>>(ws);          // zero barrier counters/flags

  k_fused<<<512, 512, 0, stream>>>(x0, xgt, vp, ap, mxp, ws, out);
}

// Round 10
// 108.611 us; speedup vs baseline: 3.7547x; 1.1448x over previous
//
#include <hip/hip_runtime.h>
#include <math.h>

// FlowMatchingLoss: B=8, M=K=2048. Log-domain pre-scaled by log2e (hw exp2/log2).
//   K_log' = sc_b * c,  sc_b = -20*log2e/(cmax_b+1e-8)
// Round-10: (1) PER-BATCH barriers (64 blocks, 4x16 tree) for all Sinkhorn
// phases -- batches decouple; one global barrier only before the combine.
// (2) Points persist in LDS across all passes: loaded raw once per block
// (prep phase + its barrier eliminated), used raw for cmax, then rescaled
// in place by n2sc/sc after sc is known. Per-pass staging = 2048 ld3 of the
// fresh potential only. All cross-block mutable data stays L3-routed via
// relaxed agent atomics (round-9 fence-free scheme; zero L2 wb/inv).

#define LOG2E 1.4426950408889634f
#define TAU   0.95238095238095238f     // 1/(1+0.05)
#define NEG20LOG2E (-28.853900817779268f)

typedef float v2f __attribute__((ext_vector_type(2)));

// workspace layout, 4-byte units
enum : int {
  OFF_LU    = 0,        // 16384: log_u * log2e   (L3-resident via atomics)
  OFF_LV    = 16384,    // 16384: log_v * log2e
  OFF_CPART = 32768,    // 512 per-block cmax partials (64/batch)
  OFF_SUMAP = 33280,    // 512 per-block sum(a) partials (64/batch)
  OFF_SWP   = 33792,    // 512 per-block sum(w)
  OFF_SEWP  = 34304,    // 512 per-block sum(w*err)
  OFF_FPART = 34816,    // 3*512 final partials (bce, sum_pi, sum_pi*klog)
  OFF_BBAR  = 36352,    // 8 batches x 512: [0..3]*32 arr | 4*32 root | (8+g)*32 rel
  OFF_GBAR  = 40448,    // global: 1024 arr | 32 root | 1024 rel
  OFF_END   = 42528
};

__device__ __forceinline__ float fexp2(float x){ return __builtin_amdgcn_exp2f(x); }
__device__ __forceinline__ float flog2(float x){ return __builtin_amdgcn_logf(x); }

// L3-coherent access (relaxed agent atomics: cache-bypass, no maintenance)
__device__ __forceinline__ float ld3(const float* p){
  return __hip_atomic_load(p, __ATOMIC_RELAXED, __HIP_MEMORY_SCOPE_AGENT);
}
__device__ __forceinline__ void st3(float* p, float v){
  __hip_atomic_store(p, v, __ATOMIC_RELAXED, __HIP_MEMORY_SCOPE_AGENT);
}

__device__ __forceinline__ float wave_sum(float v){
  #pragma unroll
  for(int m=32;m;m>>=1) v += __shfl_xor(v,m,64);
  return v;
}
__device__ __forceinline__ float wave_max(float v){
  #pragma unroll
  for(int m=32;m;m>>=1) v = fmaxf(v,__shfl_xor(v,m,64));
  return v;
}

// per-batch fence-free barrier: 64 blocks, 4 groups of 16 -> root ->
// 4 release flags; leaders spin on own group's flag (16 pollers/line).
// Monotonic phase per batch; zeroed by k_init each launch.
__device__ __forceinline__ void bbar(unsigned* bbase, int phase, int blk){
  __syncthreads();
  if(threadIdx.x == 0){
    asm volatile("s_waitcnt vmcnt(0)" ::: "memory");   // stores reached L3
    const int g = (blk>>4)&3;
    unsigned* garr = bbase + g*32;
    unsigned* root = bbase + 4*32;
    unsigned* grel = bbase + (8+g)*32;
    const unsigned va = __hip_atomic_fetch_add(garr, 1u, __ATOMIC_RELAXED,
                                               __HIP_MEMORY_SCOPE_AGENT);
    if(va == (unsigned)(16*phase - 1)){
      const unsigned vr = __hip_atomic_fetch_add(root, 1u, __ATOMIC_RELAXED,
                                                 __HIP_MEMORY_SCOPE_AGENT);
      if(vr == (unsigned)(4*phase - 1)){
        #pragma unroll
        for(int g2=0; g2<4; ++g2)
          __hip_atomic_store(bbase + (8+g2)*32, (unsigned)phase,
                             __ATOMIC_RELAXED, __HIP_MEMORY_SCOPE_AGENT);
      }
    }
    while(__hip_atomic_load(grel, __ATOMIC_RELAXED, __HIP_MEMORY_SCOPE_AGENT)
          < (unsigned)phase)
      __builtin_amdgcn_s_sleep(1);
    asm volatile("" ::: "memory");
  }
  __syncthreads();
}

// one-shot global barrier (before combine): 32 groups of 16
__device__ __forceinline__ void gbar_all(unsigned* bar, int blk){
  __syncthreads();
  if(threadIdx.x == 0){
    asm volatile("s_waitcnt vmcnt(0)" ::: "memory");
    const int g = blk & 31;
    unsigned* garr = bar + g*32;
    unsigned* root = bar + 1024;
    unsigned* grel = bar + 1056 + g*32;
    const unsigned va = __hip_atomic_fetch_add(garr, 1u, __ATOMIC_RELAXED,
                                               __HIP_MEMORY_SCOPE_AGENT);
    if(va == 15u){
      const unsigned vr = __hip_atomic_fetch_add(root, 1u, __ATOMIC_RELAXED,
                                                 __HIP_MEMORY_SCOPE_AGENT);
      if(vr == 31u){
        #pragma unroll 8
        for(int g2=0; g2<32; ++g2)
          __hip_atomic_store(bar + 1056 + g2*32, 1u,
                             __ATOMIC_RELAXED, __HIP_MEMORY_SCOPE_AGENT);
      }
    }
    while(__hip_atomic_load(grel, __ATOMIC_RELAXED, __HIP_MEMORY_SCOPE_AGENT)
          < 1u)
      __builtin_amdgcn_s_sleep(1);
    asm volatile("" ::: "memory");
  }
  __syncthreads();
}

__global__ __launch_bounds__(256) void k_init(float* ws){
  unsigned* bar = reinterpret_cast<unsigned*>(ws);
  for(int i=threadIdx.x; i<OFF_END-OFF_BBAR; i+=256) bar[OFF_BBAR+i] = 0u;
}

// one lse half-iteration. Points already scaled in LDS (pt = n2sc*xyz, sc*n2).
// Shared per k: wk = pt.w + sL[k]. Per row-pair: 3 pk-fma + exp2 + pk-add.
// Row constant sc*|A|^2 hoisted into the log2 epilogue (fragments stay RAW).
#define LSE_PASS(ROWV, FIRSTV, PH) {                                          \
    const float4* sPT = ROWV ? sB : sA;                                       \
    float* lo = ws + (ROWV?OFF_LV:OFF_LU) + 2048*b;                           \
    float* op = ws + (ROWV?OFF_LU:OFF_LV);                                    \
    const float4 A0=ROWV?AR[0]:AC[0], A1=ROWV?AR[1]:AC[1],                    \
                 A2=ROWV?AR[2]:AC[2], A3=ROWV?AR[3]:AC[3];                    \
    for(int i=tid;i<2048;i+=512) sL[i] = FIRSTV ? 0.0f : ld3(lo+i);           \
    __syncthreads();                                                          \
    const v2f ax01={A0.x,A1.x}, ay01={A0.y,A1.y}, az01={A0.z,A1.z};           \
    const v2f ax23={A2.x,A3.x}, ay23={A2.y,A3.y}, az23={A2.z,A3.z};           \
    v2f s01={0.0f,0.0f}, s23={0.0f,0.0f};                                     \
    _Pragma("unroll 2")                                                       \
    for(int k=lane;k<2048;k+=64){                                             \
      const float4 pt = sPT[k];                                               \
      const float wk = pt.w + sL[k];                                          \
      const v2f px={pt.x,pt.x}, py={pt.y,pt.y}, pz={pt.z,pt.z}, pw={wk,wk};   \
      const v2f c01 = __builtin_elementwise_fma(ax01,px,                      \
                      __builtin_elementwise_fma(ay01,py,                      \
                      __builtin_elementwise_fma(az01,pz,pw)));                \
      const v2f c23 = __builtin_elementwise_fma(ax23,px,                      \
                      __builtin_elementwise_fma(ay23,py,                      \
                      __builtin_elementwise_fma(az23,pz,pw)));                \
      s01 += (v2f){fexp2(c01.x), fexp2(c01.y)};                               \
      s23 += (v2f){fexp2(c23.x), fexp2(c23.y)};                               \
    }                                                                         \
    const float s0=wave_sum(s01.x), s1=wave_sum(s01.y);                       \
    const float s2=wave_sum(s23.x), s3=wave_sum(s23.y);                       \
    if(lane==0){                                                              \
      st3(op+r0g  , TAU*((ROWV?la[0]:lb2) - fmaf(sc,A0.w,flog2(s0))));        \
      st3(op+r0g+1, TAU*((ROWV?la[1]:lb2) - fmaf(sc,A1.w,flog2(s1))));        \
      st3(op+r0g+2, TAU*((ROWV?la[2]:lb2) - fmaf(sc,A2.w,flog2(s2))));        \
      st3(op+r0g+3, TAU*((ROWV?la[3]:lb2) - fmaf(sc,A3.w,flog2(s3))));        \
    }                                                                         \
    bbar(bbase, PH, blk);                                                     \
  }

__global__ __launch_bounds__(512,4) void k_fused(const float* __restrict__ x0,
                                                 const float* __restrict__ xgt,
                                                 const float* __restrict__ vp,
                                                 const float* __restrict__ ap,
                                                 const float* __restrict__ mxp,
                                                 float* __restrict__ ws,
                                                 float* __restrict__ out){
  __shared__ float4 sA[2048];       // batch A points (raw -> scaled in place)
  __shared__ float4 sB[2048];       // batch B points (raw -> scaled in place)
  __shared__ float  sL[2048];       // per-pass incoming potential
  __shared__ float  sa32[32], sla[32], sal[32];
  __shared__ float  sred[24];
  const int blk = blockIdx.x, tid = threadIdx.x, lane = tid&63, wid = tid>>6;
  const int b = blk>>6, j = blk&63;               // batch, block-in-batch
  const int r0l = j*32 + (wid<<2);                // batch-local row of wave
  const int r0g = b*2048 + r0l;                   // global row
  unsigned* bbase = reinterpret_cast<unsigned*>(ws) + OFF_BBAR + b*512;
  unsigned* gb    = reinterpret_cast<unsigned*>(ws) + OFF_GBAR;

  // ---- local prep: load batch points raw, own-row alpha head ----
  for(int i=tid;i<2048;i+=512){
    const int gi = (b*2048 + i)*3;
    const float x = x0[gi], y = x0[gi+1], z = x0[gi+2];
    sA[i] = make_float4(x,y,z, x*x+y*y+z*z);
    const float gx = xgt[gi], gy = xgt[gi+1], gz = xgt[gi+2];
    sB[i] = make_float4(gx,gy,gz, gx*gx+gy*gy+gz*gz);
  }
  if(wid == 0){
    float a_=0.0f, w_=0.0f, se_=0.0f;
    if(lane < 32){
      const int row = b*2048 + j*32 + lane;
      const float al = ap[row];
      const float a = 1.0f/(1.0f + fexp2(-10.0f*tanhf(al*0.1f)*LOG2E));
      sa32[lane] = a;
      sla[lane]  = flog2(fmaxf(a,1e-30f));
      sal[lane]  = al;
      const float w = 1.0f/(1.0f + fexp2(-al*LOG2E));
      const float x = x0[row*3], y = x0[row*3+1], z = x0[row*3+2];
      const float tx = mxp[row*3]-x, ty = mxp[row*3+1]-y, tz = mxp[row*3+2]-z;
      const float dx = vp[row*3]-tx, dy = vp[row*3+1]-ty, dz = vp[row*3+2]-tz;
      a_ = a; w_ = w; se_ = (dx*dx+dy*dy+dz*dz)*w;
    }
    const float sa_s = wave_sum(a_), sw_s = wave_sum(w_), sew_s = wave_sum(se_);
    if(lane == 0){
      st3(ws+OFF_SUMAP+blk, sa_s);
      st3(ws+OFF_SWP  +blk, sw_s);
      st3(ws+OFF_SEWP +blk, sew_s);
    }
  }
  __syncthreads();

  // own-row fragments (RAW, persist across all passes) + alpha registers
  float4 AR[4], AC[4]; float la[4], av[4], alv[4];
  #pragma unroll
  for(int r=0;r<4;r++){
    AR[r] = sA[r0l+r]; AC[r] = sB[r0l+r];
    la[r] = sla[(wid<<2)+r]; av[r] = sa32[(wid<<2)+r]; alv[r] = sal[(wid<<2)+r];
  }

  // ---- phase 1: cmax (raw points) ----
  {
    float c0=0,c1=0,c2=0,c3=0;                    // init 0 == clamp at 0
    #pragma unroll 2
    for(int k=lane;k<2048;k+=64){
      const float4 pt = sB[k];
      float d;
      d = AR[0].x*pt.x+AR[0].y*pt.y+AR[0].z*pt.z; c0=fmaxf(c0, AR[0].w+pt.w-2.0f*d);
      d = AR[1].x*pt.x+AR[1].y*pt.y+AR[1].z*pt.z; c1=fmaxf(c1, AR[1].w+pt.w-2.0f*d);
      d = AR[2].x*pt.x+AR[2].y*pt.y+AR[2].z*pt.z; c2=fmaxf(c2, AR[2].w+pt.w-2.0f*d);
      d = AR[3].x*pt.x+AR[3].y*pt.y+AR[3].z*pt.z; c3=fmaxf(c3, AR[3].w+pt.w-2.0f*d);
    }
    const float cmv = wave_max(fmaxf(fmaxf(c0,c1),fmaxf(c2,c3)));
    if(lane==0) sred[wid] = cmv;
    __syncthreads();
    if(tid==0){
      float m = sred[0];
      #pragma unroll
      for(int i=1;i<8;i++) m = fmaxf(m, sred[i]);
      st3(ws+OFF_CPART+blk, m);
    }
  }
  bbar(bbase, 1, blk);

  // ---- per-batch constants (lane indexes the batch's 64 block partials) ----
  const float cm = wave_max(ld3(ws+OFF_CPART + b*64 + lane));
  const float sc = NEG20LOG2E/(cm + 1e-8f);
  const float n2sc = -2.0f*sc;
  const float sav = wave_sum(ld3(ws+OFF_SUMAP + b*64 + lane));
  const float lb2 = flog2(fmaxf(sav*(1.0f/2048.0f), 1e-30f));

  // ---- rescale LDS points in place (pt = {n2sc*xyz, sc*|.|^2}) ----
  for(int i=tid;i<2048;i+=512){
    const float4 qa = sA[i];
    sA[i] = make_float4(n2sc*qa.x, n2sc*qa.y, n2sc*qa.z, sc*qa.w);
    const float4 qb = sB[i];
    sB[i] = make_float4(n2sc*qb.x, n2sc*qb.y, n2sc*qb.z, sc*qb.w);
  }
  __syncthreads();

  // ---- phases 2..11: 5 Sinkhorn iterations (row, col), per-batch sync ----
  LSE_PASS(true,  true,  2)
  LSE_PASS(false, false, 3)
  LSE_PASS(true,  false, 4)
  LSE_PASS(false, false, 5)
  LSE_PASS(true,  false, 6)
  LSE_PASS(false, false, 7)
  LSE_PASS(true,  false, 8)
  LSE_PASS(false, false, 9)
  LSE_PASS(true,  false, 10)
  LSE_PASS(false, false, 11)

  // ---- final pi pass (hoisted cr = sc|A|^2 + lu; S,Q,L accums) ----
  {
    float* lv = ws + OFF_LV + 2048*b;
    for(int i=tid;i<2048;i+=512) sL[i] = ld3(lv+i);
    __syncthreads();
    const float lu0=ld3(ws+OFF_LU+r0g),   lu1=ld3(ws+OFF_LU+r0g+1);
    const float lu2=ld3(ws+OFF_LU+r0g+2), lu3=ld3(ws+OFF_LU+r0g+3);
    const v2f ax01={AR[0].x,AR[1].x}, ay01={AR[0].y,AR[1].y}, az01={AR[0].z,AR[1].z};
    const v2f ax23={AR[2].x,AR[3].x}, ay23={AR[2].y,AR[3].y}, az23={AR[2].z,AR[3].z};
    v2f S01={0.0f,0.0f},S23={0.0f,0.0f};   // sum exp2(argp)
    v2f Q01={0.0f,0.0f},Q23={0.0f,0.0f};   // sum exp2(argp)*argp
    v2f L01={0.0f,0.0f},L23={0.0f,0.0f};   // sum exp2(argp)*lv_k
    #pragma unroll 2
    for(int k=lane;k<2048;k+=64){
      const float4 pt = sB[k];
      const float lvk = sL[k];
      const float wk = pt.w + lvk;
      const v2f px={pt.x,pt.x}, py={pt.y,pt.y}, pz={pt.z,pt.z}, pw={wk,wk};
      const v2f lk={lvk,lvk};
      const v2f c01 = __builtin_elementwise_fma(ax01,px,
                      __builtin_elementwise_fma(ay01,py,
                      __builtin_elementwise_fma(az01,pz,pw)));
      const v2f c23 = __builtin_elementwise_fma(ax23,px,
                      __builtin_elementwise_fma(ay23,py,
                      __builtin_elementwise_fma(az23,pz,pw)));
      const v2f p01 = {fexp2(c01.x), fexp2(c01.y)};
      const v2f p23 = {fexp2(c23.x), fexp2(c23.y)};
      S01 += p01;                      S23 += p23;
      Q01 = __builtin_elementwise_fma(p01,c01,Q01);
      Q23 = __builtin_elementwise_fma(p23,c23,Q23);
      L01 = __builtin_elementwise_fma(p01,lk,L01);
      L23 = __builtin_elementwise_fma(p23,lk,L23);
    }
    float S[4]={wave_sum(S01.x),wave_sum(S01.y),wave_sum(S23.x),wave_sum(S23.y)};
    float Q[4]={wave_sum(Q01.x),wave_sum(Q01.y),wave_sum(Q23.x),wave_sum(Q23.y)};
    float L[4]={wave_sum(L01.x),wave_sum(L01.y),wave_sum(L23.x),wave_sum(L23.y)};
    const float lus[4]={lu0,lu1,lu2,lu3};
    float spc = 0.0f, bce = 0.0f, spt = 0.0f;
    #pragma unroll
    for(int r=0;r<4;r++){
      const float cr = fmaf(sc, AR[r].w, lus[r]);   // hoisted row constant
      const float p2 = fexp2(cr);
      const float sp = p2*S[r];                     // true row sum of pi
      // sum(pi*arg_true) = p2*(Q + cr*S); klog = arg_true - lu - lv
      spc += p2*fmaf(cr,S[r],Q[r]) - p2*L[r] - lus[r]*sp;
      float yv = sp / (av[r] + 1e-8f);
      yv = fminf(fmaxf(yv,0.0f),1.0f);
      const float al = alv[r];
      bce += fmaxf(al,0.0f) - al*yv
           + 0.69314718056f*flog2(1.0f + fexp2(-fabsf(al)*LOG2E));
      spt += sp;
    }
    if(lane==0){ sred[wid]=bce; sred[8+wid]=spt; sred[16+wid]=spc; }
    __syncthreads();
    if(tid==0){
      float tb=0, ts=0, tc=0;
      #pragma unroll
      for(int i=0;i<8;i++){ tb+=sred[i]; ts+=sred[8+i]; tc+=sred[16+i]; }
      st3(ws+OFF_FPART +        blk, tb);
      st3(ws+OFF_FPART + 512  + blk, ts);
      st3(ws+OFF_FPART + 1024 + blk, tc);
    }
  }
  gbar_all(gb, blk);

  // ---- combine (block 0 only) ----
  if(blk == 0){
    float pb = ld3(ws+OFF_FPART+tid);
    float ps = ld3(ws+OFF_FPART+512+tid);
    float pc = ld3(ws+OFF_FPART+1024+tid);
    float pw = ld3(ws+OFF_SWP+tid);
    float pe = ld3(ws+OFF_SEWP+tid);
    pb=wave_sum(pb); ps=wave_sum(ps); pc=wave_sum(pc);
    pw=wave_sum(pw); pe=wave_sum(pe);
    if(lane==0){
      sL[wid*5+0]=pb; sL[wid*5+1]=ps; sL[wid*5+2]=pc;
      sL[wid*5+3]=pw; sL[wid*5+4]=pe;
    }
    __syncthreads();
    if(tid==0){
      float bce=0, sp=0, spc=0, sw=0, sew=0;
      #pragma unroll
      for(int w=0;w<8;w++){
        bce+=sL[w*5+0]; sp+=sL[w*5+1]; spc+=sL[w*5+2];
        sw +=sL[w*5+3]; sew+=sL[w*5+4];
      }
      const float loss_vel  = sew / fmaxf(sw, 1.0f);
      const float loss_surv = bce / 16384.0f;
      // sum(pi*cost_n) = spc * (-ln2/20)  since klog = -20*log2e*cost_n
      const float loss_tr = (spc * (-0.03465735902799726f)) / fmaxf(sp, 1e-8f);
      out[0] = loss_vel + loss_surv + 0.1f*loss_tr;
    }
  }
}

extern "C" void kernel_launch(void* const* d_in, const int* in_sizes, int n_in,
                              void* d_out, int out_size, void* d_ws, size_t ws_size,
                              hipStream_t stream) {
  (void)in_sizes; (void)n_in; (void)out_size; (void)ws_size;
  const float* x0  = (const float*)d_in[0];
  const float* xgt = (const float*)d_in[1];
  const float* vp  = (const float*)d_in[2];
  const float* ap  = (const float*)d_in[3];
  const float* mxp = (const float*)d_in[5];   // t (d_in[4]) unused
  float* ws  = (float*)d_ws;
  float* out = (float*)d_out;

  k_init<<<1, 256, 0, stream>>>(ws);          // zero all barrier words

  k_fused<<<512, 512, 0, stream>>>(x0, xgt, vp, ap, mxp, ws, out);
}